// Round 6
// baseline (877.905 us; speedup 1.0000x reference)
//
#include <hip/hip_runtime.h>
#include <hip/hip_bf16.h>

// Problem constants (reference: B=32, S=2048, D=1024, F=512, E=8, GROUP=32 -> 1 group)
#define SS 2048
#define BB 32
#define DD 1024
#define FF 512
#define EE 8

// DIAGNOSTIC ROUND: logits_k/merge_v/emit_out bodies replicated (identical
// outputs each rep; pointers laundered so loads can't be hoisted) to push
// them past the 155-us fill threshold into rocprof top-5. Revert next round.
#define REP_LOGITS 5
#define REP_MERGE 6
#define REP_EMIT 5

typedef __attribute__((ext_vector_type(8))) short short8;
typedef __attribute__((ext_vector_type(8))) unsigned short ushort8v;
typedef __attribute__((ext_vector_type(4))) unsigned short ushort4v;
typedef __attribute__((ext_vector_type(4))) float f32x4;

__device__ inline unsigned short f2bf(float f) {
  union { float f; unsigned u; } v; v.f = f;
  return (unsigned short)((v.u + 0x7FFFu + ((v.u >> 16) & 1u)) >> 16);
}
__device__ inline float bf2f(unsigned short h) {
  union { unsigned u; float f; } v; v.u = ((unsigned)h) << 16;
  return v.f;
}

// ---------------- transpose + fp32->bf16 cast: in (E,K,N) f32 -> out (E,N,K) bf16
__global__ __launch_bounds__(256) void transpose_bf16(
    const float* __restrict__ in, unsigned short* __restrict__ out, int K, int N) {
  __shared__ float tile[32][33];
  int e = blockIdx.z;
  const float* inp = in + (size_t)e * K * N;
  unsigned short* outp = out + (size_t)e * K * N;
  int k0 = blockIdx.x * 32, n0 = blockIdx.y * 32;
  int tx = threadIdx.x;   // 0..31
  int ty = threadIdx.y;   // 0..7
#pragma unroll
  for (int i = 0; i < 4; i++) {
    int k = ty + i * 8;
    tile[k][tx] = inp[(size_t)(k0 + k) * N + n0 + tx];
  }
  __syncthreads();
#pragma unroll
  for (int i = 0; i < 4; i++) {
    int n = ty + i * 8;
    outp[(size_t)(n0 + n) * K + k0 + tx] = f2bf(tile[tx][n]);
  }
}

// ---------------- logits: lgT[s,k,e] = x_row[m=k*S+s] . ctrl[:,e]
__global__ __launch_bounds__(256) void logits_k(
    const float* __restrict__ x,      // (B,S,D) f32: row m = k*S + s
    const float* __restrict__ ctrl,   // (D,E) f32
    float* __restrict__ lgT) {        // (S,B,E) f32
  int t = threadIdx.x;
  __shared__ __align__(16) float cs[EE * DD];   // 32 KiB, [e][swz(d)]
  for (int i = t; i < DD * EE; i += 256) {
    int d = i >> 3, e = i & 7;
    cs[e * DD + (d ^ (((d >> 6) & 7) << 2))] = ctrl[i];
  }
  __syncthreads();

  int g = t >> 4, c = t & 15;
  int m0 = blockIdx.x * 64 + g * 4;

  for (int rep = 0; rep < REP_LOGITS; ++rep) {
    const float* xr = x + (size_t)m0 * DD;
    asm volatile("" : "+v"(xr));    // launder: defeat load hoisting across reps
    float acc[4][8] = {};
#pragma unroll 4
    for (int i = 0; i < 16; i++) {
      int db = c * 4 + i * 64;
      float4 c4[8];
#pragma unroll
      for (int e = 0; e < 8; e++)
        c4[e] = *(const float4*)&cs[e * DD + i * 64 + ((c ^ (i & 7)) << 2)];
#pragma unroll
      for (int r = 0; r < 4; r++) {
        float4 xv = *(const float4*)&xr[(size_t)r * DD + db];
#pragma unroll
        for (int e = 0; e < 8; e++)
          acc[r][e] += xv.x * c4[e].x + xv.y * c4[e].y + xv.z * c4[e].z + xv.w * c4[e].w;
      }
    }
#pragma unroll
    for (int off = 1; off < 16; off <<= 1)
#pragma unroll
      for (int r = 0; r < 4; r++)
#pragma unroll
        for (int e = 0; e < 8; e++)
          acc[r][e] += __shfl_xor(acc[r][e], off, 64);
    if (c == 0) {
#pragma unroll
      for (int r = 0; r < 4; r++) {
        int m = m0 + r;
        int s = m & (SS - 1), k = m >> 11;
        float* p = &lgT[((size_t)s * BB + k) * EE];
        float4 lo = {acc[r][0], acc[r][1], acc[r][2], acc[r][3]};
        float4 hi = {acc[r][4], acc[r][5], acc[r][6], acc[r][7]};
        *(float4*)p = lo;
        *(float4*)(p + 4) = hi;
      }
    }
  }
}

// ---------------- softmax over tokens k per (s,e); 8 s per block
__global__ __launch_bounds__(256) void softmax_k(
    const float* __restrict__ lgT,   // (S,B,E) f32
    float* __restrict__ mw) {        // (S,B,E) f32
  int t = threadIdx.x;
  int sl = t >> 5, k = t & 31;
  size_t s = (size_t)blockIdx.x * 8 + sl;
  const float* p = &lgT[(s * BB + k) * EE];
  float v[8];
  float4 lo = *(const float4*)p, hi = *(const float4*)(p + 4);
  v[0]=lo.x; v[1]=lo.y; v[2]=lo.z; v[3]=lo.w; v[4]=hi.x; v[5]=hi.y; v[6]=hi.z; v[7]=hi.w;
  float mx[8];
#pragma unroll
  for (int e = 0; e < 8; e++) mx[e] = v[e];
#pragma unroll
  for (int off = 1; off < 32; off <<= 1)
#pragma unroll
    for (int e = 0; e < 8; e++)
      mx[e] = fmaxf(mx[e], __shfl_xor(mx[e], off, 64));
  float pr[8], sm[8];
#pragma unroll
  for (int e = 0; e < 8; e++) { pr[e] = __expf(v[e] - mx[e]); sm[e] = pr[e]; }
#pragma unroll
  for (int off = 1; off < 32; off <<= 1)
#pragma unroll
    for (int e = 0; e < 8; e++)
      sm[e] += __shfl_xor(sm[e], off, 64);
  float4 o0 = {pr[0]/sm[0], pr[1]/sm[1], pr[2]/sm[2], pr[3]/sm[3]};
  float4 o1 = {pr[4]/sm[4], pr[5]/sm[5], pr[6]/sm[6], pr[7]/sm[7]};
  float* q = &mw[(s * BB + k) * EE];
  *(float4*)q = o0;
  *(float4*)(q + 4) = o1;
}

// ---------------- merge: merged[s,e,d] = sum_k mw[s,k,e] * x[k,s,d]
__global__ __launch_bounds__(256) void merge_v(
    const float* __restrict__ x,          // (B,S,D) f32
    const float* __restrict__ mw,         // (S,B,E) f32
    unsigned short* __restrict__ merged) {// (S,E,D) bf16
  int s = blockIdx.x;
  int t = threadIdx.x;
  __shared__ __align__(16) float wl[BB][EE];
  wl[t >> 3][t & 7] = mw[(size_t)s * BB * EE + t];
  __syncthreads();
  int d0 = t * 4;
  for (int rep = 0; rep < REP_MERGE; ++rep) {
    const float* xp = x;
    asm volatile("" : "+v"(xp));    // launder
    float a[8][4] = {};
#pragma unroll 4
    for (int k = 0; k < 32; k++) {
      float4 xv = *(const float4*)&xp[((size_t)k * SS + s) * DD + d0];
      float4 wA = *(const float4*)&wl[k][0];
      float4 wB = *(const float4*)&wl[k][4];
      a[0][0] += wA.x * xv.x; a[0][1] += wA.x * xv.y; a[0][2] += wA.x * xv.z; a[0][3] += wA.x * xv.w;
      a[1][0] += wA.y * xv.x; a[1][1] += wA.y * xv.y; a[1][2] += wA.y * xv.z; a[1][3] += wA.y * xv.w;
      a[2][0] += wA.z * xv.x; a[2][1] += wA.z * xv.y; a[2][2] += wA.z * xv.z; a[2][3] += wA.z * xv.w;
      a[3][0] += wA.w * xv.x; a[3][1] += wA.w * xv.y; a[3][2] += wA.w * xv.z; a[3][3] += wA.w * xv.w;
      a[4][0] += wB.x * xv.x; a[4][1] += wB.x * xv.y; a[4][2] += wB.x * xv.z; a[4][3] += wB.x * xv.w;
      a[5][0] += wB.y * xv.x; a[5][1] += wB.y * xv.y; a[5][2] += wB.y * xv.z; a[5][3] += wB.y * xv.w;
      a[6][0] += wB.z * xv.x; a[6][1] += wB.z * xv.y; a[6][2] += wB.z * xv.z; a[6][3] += wB.z * xv.w;
      a[7][0] += wB.w * xv.x; a[7][1] += wB.w * xv.y; a[7][2] += wB.w * xv.z; a[7][3] += wB.w * xv.w;
    }
#pragma unroll
    for (int e = 0; e < 8; e++) {
      ushort4v pv;
      pv[0] = f2bf(a[e][0]); pv[1] = f2bf(a[e][1]);
      pv[2] = f2bf(a[e][2]); pv[3] = f2bf(a[e][3]);
      *(ushort4v*)&merged[((size_t)s * EE + e) * DD + d0] = pv;
    }
  }
}

// ---------------- bf16 MFMA GEMM with global_load_lds staging (m97 pattern)
// A: (S, E, K) bf16 ; Bt: (E, N, K) bf16 ; C: (S, E, N) bf16
template <int RELU>
__global__ __launch_bounds__(256) void gemm_bt(
    const unsigned short* __restrict__ A, const unsigned short* __restrict__ Bt,
    unsigned short* __restrict__ C, int K, int N) {
  int e = blockIdx.z;
  int m0 = blockIdx.x * 128;
  int n0 = blockIdx.y * 128;
  const int lda = EE * K;
  const unsigned short* Ae = A + (size_t)e * K;
  const unsigned short* Be = Bt + (size_t)e * N * K;

  __shared__ __align__(16) unsigned short As[128 * 32];  // linear, 8 KiB
  __shared__ __align__(16) unsigned short Bs[128 * 32];

  int t = threadIdx.x;
  int lane = t & 63, w = t >> 6;
  int wm = w >> 1, wn = w & 1;
  int lr = lane & 15;
  int kh = lane >> 4;
  int khs = kh ^ ((lr >> 1) & 3);

  f32x4 acc[4][4] = {};

  for (int kt = 0; kt < K; kt += 32) {
#pragma unroll
    for (int i = 0; i < 2; i++) {
      int c = t + i * 256;
      int r = c >> 2;
      int subg = (c & 3) ^ ((r >> 1) & 3);
      __builtin_amdgcn_global_load_lds(
          (const __attribute__((address_space(1))) void*)(Ae + (size_t)(m0 + r) * lda + kt + subg * 8),
          (__attribute__((address_space(3))) void*)(&As[c * 8]), 16, 0, 0);
      __builtin_amdgcn_global_load_lds(
          (const __attribute__((address_space(1))) void*)(Be + (size_t)(n0 + r) * K + kt + subg * 8),
          (__attribute__((address_space(3))) void*)(&Bs[c * 8]), 16, 0, 0);
    }
    __syncthreads();

    short8 af[4], bfr[4];
#pragma unroll
    for (int mi = 0; mi < 4; mi++)
      af[mi] = *(const short8*)&As[(wm * 64 + mi * 16 + lr) * 32 + khs * 8];
#pragma unroll
    for (int ni = 0; ni < 4; ni++)
      bfr[ni] = *(const short8*)&Bs[(wn * 64 + ni * 16 + lr) * 32 + khs * 8];
#pragma unroll
    for (int mi = 0; mi < 4; mi++)
#pragma unroll
      for (int ni = 0; ni < 4; ni++)
        acc[mi][ni] = __builtin_amdgcn_mfma_f32_16x16x32_bf16(af[mi], bfr[ni], acc[mi][ni], 0, 0, 0);
    __syncthreads();
  }

  int rb = (lane >> 4) * 4;
  int cb = lane & 15;
#pragma unroll
  for (int mi = 0; mi < 4; mi++)
#pragma unroll
    for (int ni = 0; ni < 4; ni++)
#pragma unroll
      for (int r = 0; r < 4; r++) {
        float v = acc[mi][ni][r];
        if (RELU) v = fmaxf(v, 0.f);
        int m = m0 + wm * 64 + mi * 16 + rb + r;
        int n = n0 + wn * 64 + ni * 16 + cb;
        C[(size_t)m * (EE * N) + (size_t)e * N + n] = f2bf(v);
      }
}

// ---------------- emit: out[b,s,d] = sum_e mw[s,b,e] * eo[s,e,d]
__global__ __launch_bounds__(256) void emit_out(
    const unsigned short* __restrict__ eo,  // (S,E,D) bf16
    const float* __restrict__ mw,           // (S,B,E) f32
    float* __restrict__ out) {              // (B,S,D) f32
  int s = blockIdx.x;
  int t = threadIdx.x;
  __shared__ float wsm[BB][EE];
  wsm[t >> 3][t & 7] = mw[(size_t)s * BB * EE + t];
  __syncthreads();
  int d0 = t * 4;
  for (int rep = 0; rep < REP_EMIT; ++rep) {
    const unsigned short* eop = eo;
    float* outp = out;
    asm volatile("" : "+v"(eop), "+v"(outp));   // launder
    float ev[EE][4];
#pragma unroll
    for (int e2 = 0; e2 < 8; e2++) {
      ushort4v v = *(const ushort4v*)&eop[((size_t)s * EE + e2) * DD + d0];
      ev[e2][0] = bf2f(v[0]); ev[e2][1] = bf2f(v[1]);
      ev[e2][2] = bf2f(v[2]); ev[e2][3] = bf2f(v[3]);
    }
    for (int b = 0; b < BB; b++) {
      float o0 = 0.f, o1 = 0.f, o2 = 0.f, o3 = 0.f;
#pragma unroll
      for (int e2 = 0; e2 < 8; e2++) {
        float we = wsm[b][e2];
        o0 += we * ev[e2][0]; o1 += we * ev[e2][1];
        o2 += we * ev[e2][2]; o3 += we * ev[e2][3];
      }
      float4 ov = {o0, o1, o2, o3};
      *(float4*)&outp[((size_t)b * SS + s) * DD + d0] = ov;
    }
  }
}

extern "C" void kernel_launch(void* const* d_in, const int* in_sizes, int n_in,
                              void* d_out, int out_size, void* d_ws, size_t ws_size,
                              hipStream_t stream) {
  const float* x = (const float*)d_in[0];        // (32, 2048, 1024)
  const float* lin1 = (const float*)d_in[1];     // (8, 1024, 512)
  const float* lin2 = (const float*)d_in[2];     // (8, 512, 1024)
  const float* ctrl = (const float*)d_in[3];     // (1024, 8)
  float* out = (float*)d_out;

  char* ws = (char*)d_ws;
  size_t off = 0;
  unsigned short* lin1t = (unsigned short*)(ws + off); off += (size_t)EE * DD * FF * 2;  // 8 MiB
  unsigned short* lin2t = (unsigned short*)(ws + off); off += (size_t)EE * FF * DD * 2;  // 8 MiB
  unsigned short* merged = (unsigned short*)(ws + off); off += (size_t)SS * EE * DD * 2; // 32 MiB
  unsigned short* hbuf = (unsigned short*)(ws + off); off += (size_t)SS * EE * FF * 2;   // 16 MiB
  unsigned short* eo = (unsigned short*)(ws + off); off += (size_t)SS * EE * DD * 2;     // 32 MiB
  float* mw = (float*)(ws + off); off += (size_t)SS * BB * EE * 4;                       // 2 MiB
  float* lgT = (float*)(ws + off); off += (size_t)SS * BB * EE * 4;                      // 2 MiB

  dim3 tb(32, 8);
  transpose_bf16<<<dim3(DD / 32, FF / 32, EE), tb, 0, stream>>>(lin1, lin1t, DD, FF);
  transpose_bf16<<<dim3(FF / 32, DD / 32, EE), tb, 0, stream>>>(lin2, lin2t, FF, DD);

  logits_k<<<(SS * BB) / 64, 256, 0, stream>>>(x, ctrl, lgT);
  softmax_k<<<SS / 8, 256, 0, stream>>>(lgT, mw);
  merge_v<<<SS, 256, 0, stream>>>(x, mw, merged);

  gemm_bt<1><<<dim3(SS / 128, FF / 128, EE), 256, 0, stream>>>(merged, lin1t, hbuf, DD, FF);
  gemm_bt<0><<<dim3(SS / 128, DD / 128, EE), 256, 0, stream>>>(hbuf, lin2t, eo, FF, DD);

  emit_out<<<SS, 256, 0, stream>>>(eo, mw, out);
}

// Round 7
// 340.595 us; speedup vs baseline: 2.5776x; 2.5776x over previous
//
#include <hip/hip_runtime.h>
#include <hip/hip_bf16.h>

// Problem constants (reference: B=32, S=2048, D=1024, F=512, E=8, GROUP=32 -> 1 group)
#define SS 2048
#define BB 32
#define DD 1024
#define FF 512
#define EE 8

typedef __attribute__((ext_vector_type(8))) short short8;
typedef __attribute__((ext_vector_type(8))) unsigned short ushort8v;
typedef __attribute__((ext_vector_type(4))) unsigned short ushort4v;
typedef __attribute__((ext_vector_type(4))) float f32x4;

__device__ inline unsigned short f2bf(float f) {
  union { float f; unsigned u; } v; v.f = f;
  return (unsigned short)((v.u + 0x7FFFu + ((v.u >> 16) & 1u)) >> 16);
}
__device__ inline float bf2f(unsigned short h) {
  union { unsigned u; float f; } v; v.u = ((unsigned)h) << 16;
  return v.f;
}

// ---------------- transpose + fp32->bf16 cast: in (E,K,N) f32 -> out (E,N,K) bf16
__global__ __launch_bounds__(256) void transpose_bf16(
    const float* __restrict__ in, unsigned short* __restrict__ out, int K, int N) {
  __shared__ float tile[32][33];
  int e = blockIdx.z;
  const float* inp = in + (size_t)e * K * N;
  unsigned short* outp = out + (size_t)e * K * N;
  int k0 = blockIdx.x * 32, n0 = blockIdx.y * 32;
  int tx = threadIdx.x;   // 0..31
  int ty = threadIdx.y;   // 0..7
#pragma unroll
  for (int i = 0; i < 4; i++) {
    int k = ty + i * 8;
    tile[k][tx] = inp[(size_t)(k0 + k) * N + n0 + tx];
  }
  __syncthreads();
#pragma unroll
  for (int i = 0; i < 4; i++) {
    int n = ty + i * 8;
    outp[(size_t)(n0 + n) * K + k0 + tx] = f2bf(tile[tx][n]);
  }
}

// ---------------- logits: lgT[s,k,e] = x_row[m=k*S+s] . ctrl[:,e]
__global__ __launch_bounds__(256) void logits_k(
    const float* __restrict__ x,      // (B,S,D) f32: row m = k*S + s
    const float* __restrict__ ctrl,   // (D,E) f32
    float* __restrict__ lgT) {        // (S,B,E) f32
  int t = threadIdx.x;
  __shared__ __align__(16) float cs[EE * DD];   // 32 KiB, [e][swz(d)]
  for (int i = t; i < DD * EE; i += 256) {
    int d = i >> 3, e = i & 7;
    cs[e * DD + (d ^ (((d >> 6) & 7) << 2))] = ctrl[i];
  }
  __syncthreads();

  int g = t >> 4, c = t & 15;
  int m0 = blockIdx.x * 64 + g * 4;
  const float* xr = x + (size_t)m0 * DD;
  float acc[4][8] = {};
#pragma unroll 4
  for (int i = 0; i < 16; i++) {
    int db = c * 4 + i * 64;
    float4 c4[8];
#pragma unroll
    for (int e = 0; e < 8; e++)
      c4[e] = *(const float4*)&cs[e * DD + i * 64 + ((c ^ (i & 7)) << 2)];
#pragma unroll
    for (int r = 0; r < 4; r++) {
      float4 xv = *(const float4*)&xr[(size_t)r * DD + db];
#pragma unroll
      for (int e = 0; e < 8; e++)
        acc[r][e] += xv.x * c4[e].x + xv.y * c4[e].y + xv.z * c4[e].z + xv.w * c4[e].w;
    }
  }
#pragma unroll
  for (int off = 1; off < 16; off <<= 1)
#pragma unroll
    for (int r = 0; r < 4; r++)
#pragma unroll
      for (int e = 0; e < 8; e++)
        acc[r][e] += __shfl_xor(acc[r][e], off, 64);
  if (c == 0) {
#pragma unroll
    for (int r = 0; r < 4; r++) {
      int m = m0 + r;
      int s = m & (SS - 1), k = m >> 11;
      float* p = &lgT[((size_t)s * BB + k) * EE];
      float4 lo = {acc[r][0], acc[r][1], acc[r][2], acc[r][3]};
      float4 hi = {acc[r][4], acc[r][5], acc[r][6], acc[r][7]};
      *(float4*)p = lo;
      *(float4*)(p + 4) = hi;
    }
  }
}

// ---------------- softmax over tokens k per (s,e); 8 s per block
__global__ __launch_bounds__(256) void softmax_k(
    const float* __restrict__ lgT,   // (S,B,E) f32
    float* __restrict__ mw) {        // (S,B,E) f32
  int t = threadIdx.x;
  int sl = t >> 5, k = t & 31;
  size_t s = (size_t)blockIdx.x * 8 + sl;
  const float* p = &lgT[(s * BB + k) * EE];
  float v[8];
  float4 lo = *(const float4*)p, hi = *(const float4*)(p + 4);
  v[0]=lo.x; v[1]=lo.y; v[2]=lo.z; v[3]=lo.w; v[4]=hi.x; v[5]=hi.y; v[6]=hi.z; v[7]=hi.w;
  float mx[8];
#pragma unroll
  for (int e = 0; e < 8; e++) mx[e] = v[e];
#pragma unroll
  for (int off = 1; off < 32; off <<= 1)
#pragma unroll
    for (int e = 0; e < 8; e++)
      mx[e] = fmaxf(mx[e], __shfl_xor(mx[e], off, 64));
  float pr[8], sm[8];
#pragma unroll
  for (int e = 0; e < 8; e++) { pr[e] = __expf(v[e] - mx[e]); sm[e] = pr[e]; }
#pragma unroll
  for (int off = 1; off < 32; off <<= 1)
#pragma unroll
    for (int e = 0; e < 8; e++)
      sm[e] += __shfl_xor(sm[e], off, 64);
  float4 o0 = {pr[0]/sm[0], pr[1]/sm[1], pr[2]/sm[2], pr[3]/sm[3]};
  float4 o1 = {pr[4]/sm[4], pr[5]/sm[5], pr[6]/sm[6], pr[7]/sm[7]};
  float* q = &mw[(s * BB + k) * EE];
  *(float4*)q = o0;
  *(float4*)(q + 4) = o1;
}

// ---------------- merge: merged[e,s,d] = sum_k mw[s,k,e] * x[k,s,d]   (E,S,D layout)
__global__ __launch_bounds__(256) void merge_v(
    const float* __restrict__ x,          // (B,S,D) f32
    const float* __restrict__ mw,         // (S,B,E) f32
    unsigned short* __restrict__ merged) {// (E,S,D) bf16
  int s = blockIdx.x;
  int t = threadIdx.x;
  __shared__ __align__(16) float wl[BB][EE];
  wl[t >> 3][t & 7] = mw[(size_t)s * BB * EE + t];
  __syncthreads();
  int d0 = t * 4;
  float a[8][4] = {};
#pragma unroll 4
  for (int k = 0; k < 32; k++) {
    float4 xv = *(const float4*)&x[((size_t)k * SS + s) * DD + d0];
    float4 wA = *(const float4*)&wl[k][0];
    float4 wB = *(const float4*)&wl[k][4];
    a[0][0] += wA.x * xv.x; a[0][1] += wA.x * xv.y; a[0][2] += wA.x * xv.z; a[0][3] += wA.x * xv.w;
    a[1][0] += wA.y * xv.x; a[1][1] += wA.y * xv.y; a[1][2] += wA.y * xv.z; a[1][3] += wA.y * xv.w;
    a[2][0] += wA.z * xv.x; a[2][1] += wA.z * xv.y; a[2][2] += wA.z * xv.z; a[2][3] += wA.z * xv.w;
    a[3][0] += wA.w * xv.x; a[3][1] += wA.w * xv.y; a[3][2] += wA.w * xv.z; a[3][3] += wA.w * xv.w;
    a[4][0] += wB.x * xv.x; a[4][1] += wB.x * xv.y; a[4][2] += wB.x * xv.z; a[4][3] += wB.x * xv.w;
    a[5][0] += wB.y * xv.x; a[5][1] += wB.y * xv.y; a[5][2] += wB.y * xv.z; a[5][3] += wB.y * xv.w;
    a[6][0] += wB.z * xv.x; a[6][1] += wB.z * xv.y; a[6][2] += wB.z * xv.z; a[6][3] += wB.z * xv.w;
    a[7][0] += wB.w * xv.x; a[7][1] += wB.w * xv.y; a[7][2] += wB.w * xv.z; a[7][3] += wB.w * xv.w;
  }
#pragma unroll
  for (int e = 0; e < 8; e++) {
    ushort4v pv;
    pv[0] = f2bf(a[e][0]); pv[1] = f2bf(a[e][1]);
    pv[2] = f2bf(a[e][2]); pv[3] = f2bf(a[e][3]);
    *(ushort4v*)&merged[((size_t)e * SS + s) * DD + d0] = pv;
  }
}

// ---------------- bf16 MFMA GEMM, dense per-expert slices (m97 pattern)
// A: (E, M=S, K) bf16 dense ; Bt: (E, N, K) bf16 ; C: (E, M, N) bf16 dense
// grid: (S/128, N/128, E), 256 threads = 4 waves (2x2), wave tile 64x64
template <int RELU>
__global__ __launch_bounds__(256) void gemm_bt(
    const unsigned short* __restrict__ A, const unsigned short* __restrict__ Bt,
    unsigned short* __restrict__ C, int K, int N) {
  int e = blockIdx.z;
  int m0 = blockIdx.x * 128;
  int n0 = blockIdx.y * 128;
  const unsigned short* Ae = A + (size_t)e * SS * K;
  const unsigned short* Be = Bt + (size_t)e * N * K;
  unsigned short* Ce = C + (size_t)e * SS * N;

  __shared__ __align__(16) unsigned short As[128 * 32];  // linear, 8 KiB
  __shared__ __align__(16) unsigned short Bs[128 * 32];

  int t = threadIdx.x;
  int lane = t & 63, w = t >> 6;
  int wm = w >> 1, wn = w & 1;
  int lr = lane & 15;
  int kh = lane >> 4;
  int khs = kh ^ ((lr >> 1) & 3);

  f32x4 acc[4][4] = {};

  for (int kt = 0; kt < K; kt += 32) {
#pragma unroll
    for (int i = 0; i < 2; i++) {
      int c = t + i * 256;
      int r = c >> 2;
      int subg = (c & 3) ^ ((r >> 1) & 3);
      __builtin_amdgcn_global_load_lds(
          (const __attribute__((address_space(1))) void*)(Ae + (size_t)(m0 + r) * K + kt + subg * 8),
          (__attribute__((address_space(3))) void*)(&As[c * 8]), 16, 0, 0);
      __builtin_amdgcn_global_load_lds(
          (const __attribute__((address_space(1))) void*)(Be + (size_t)(n0 + r) * K + kt + subg * 8),
          (__attribute__((address_space(3))) void*)(&Bs[c * 8]), 16, 0, 0);
    }
    __syncthreads();

    short8 af[4], bfr[4];
#pragma unroll
    for (int mi = 0; mi < 4; mi++)
      af[mi] = *(const short8*)&As[(wm * 64 + mi * 16 + lr) * 32 + khs * 8];
#pragma unroll
    for (int ni = 0; ni < 4; ni++)
      bfr[ni] = *(const short8*)&Bs[(wn * 64 + ni * 16 + lr) * 32 + khs * 8];
#pragma unroll
    for (int mi = 0; mi < 4; mi++)
#pragma unroll
      for (int ni = 0; ni < 4; ni++)
        acc[mi][ni] = __builtin_amdgcn_mfma_f32_16x16x32_bf16(af[mi], bfr[ni], acc[mi][ni], 0, 0, 0);
    __syncthreads();
  }

  int rb = (lane >> 4) * 4;
  int cb = lane & 15;
#pragma unroll
  for (int mi = 0; mi < 4; mi++)
#pragma unroll
    for (int ni = 0; ni < 4; ni++)
#pragma unroll
      for (int r = 0; r < 4; r++) {
        float v = acc[mi][ni][r];
        if (RELU) v = fmaxf(v, 0.f);
        int m = m0 + wm * 64 + mi * 16 + rb + r;
        int n = n0 + wn * 64 + ni * 16 + cb;
        Ce[(size_t)m * N + n] = f2bf(v);
      }
}

// ---------------- emit: out[b,s,d] = sum_e mw[s,b,e] * eo[e,s,d]
__global__ __launch_bounds__(256) void emit_out(
    const unsigned short* __restrict__ eo,  // (E,S,D) bf16
    const float* __restrict__ mw,           // (S,B,E) f32
    float* __restrict__ out) {              // (B,S,D) f32
  int s = blockIdx.x;
  int t = threadIdx.x;
  __shared__ float wsm[BB][EE];
  wsm[t >> 3][t & 7] = mw[(size_t)s * BB * EE + t];
  __syncthreads();
  int d0 = t * 4;
  float ev[EE][4];
#pragma unroll
  for (int e2 = 0; e2 < 8; e2++) {
    ushort4v v = *(const ushort4v*)&eo[((size_t)e2 * SS + s) * DD + d0];
    ev[e2][0] = bf2f(v[0]); ev[e2][1] = bf2f(v[1]);
    ev[e2][2] = bf2f(v[2]); ev[e2][3] = bf2f(v[3]);
  }
  for (int b = 0; b < BB; b++) {
    float o0 = 0.f, o1 = 0.f, o2 = 0.f, o3 = 0.f;
#pragma unroll
    for (int e2 = 0; e2 < 8; e2++) {
      float we = wsm[b][e2];
      o0 += we * ev[e2][0]; o1 += we * ev[e2][1];
      o2 += we * ev[e2][2]; o3 += we * ev[e2][3];
    }
    float4 ov = {o0, o1, o2, o3};
    *(float4*)&out[((size_t)b * SS + s) * DD + d0] = ov;
  }
}

extern "C" void kernel_launch(void* const* d_in, const int* in_sizes, int n_in,
                              void* d_out, int out_size, void* d_ws, size_t ws_size,
                              hipStream_t stream) {
  const float* x = (const float*)d_in[0];        // (32, 2048, 1024)
  const float* lin1 = (const float*)d_in[1];     // (8, 1024, 512)
  const float* lin2 = (const float*)d_in[2];     // (8, 512, 1024)
  const float* ctrl = (const float*)d_in[3];     // (1024, 8)
  float* out = (float*)d_out;

  char* ws = (char*)d_ws;
  size_t off = 0;
  unsigned short* lin1t = (unsigned short*)(ws + off); off += (size_t)EE * DD * FF * 2;  // 8 MiB
  unsigned short* lin2t = (unsigned short*)(ws + off); off += (size_t)EE * FF * DD * 2;  // 8 MiB
  unsigned short* merged = (unsigned short*)(ws + off); off += (size_t)SS * EE * DD * 2; // 32 MiB (E,S,D)
  unsigned short* hbuf = (unsigned short*)(ws + off); off += (size_t)SS * EE * FF * 2;   // 16 MiB (E,S,F)
  unsigned short* eo = (unsigned short*)(ws + off); off += (size_t)SS * EE * DD * 2;     // 32 MiB (E,S,D)
  float* mw = (float*)(ws + off); off += (size_t)SS * BB * EE * 4;                       // 2 MiB
  float* lgT = (float*)(ws + off); off += (size_t)SS * BB * EE * 4;                      // 2 MiB

  dim3 tb(32, 8);
  transpose_bf16<<<dim3(DD / 32, FF / 32, EE), tb, 0, stream>>>(lin1, lin1t, DD, FF);
  transpose_bf16<<<dim3(FF / 32, DD / 32, EE), tb, 0, stream>>>(lin2, lin2t, FF, DD);

  logits_k<<<(SS * BB) / 64, 256, 0, stream>>>(x, ctrl, lgT);
  softmax_k<<<SS / 8, 256, 0, stream>>>(lgT, mw);
  merge_v<<<SS, 256, 0, stream>>>(x, mw, merged);

  // h = relu(merged @ lin1): per-expert dense M=S, K=D, N=F
  gemm_bt<1><<<dim3(SS / 128, FF / 128, EE), 256, 0, stream>>>(merged, lin1t, hbuf, DD, FF);
  // eo = h @ lin2: K=F, N=D
  gemm_bt<0><<<dim3(SS / 128, DD / 128, EE), 256, 0, stream>>>(hbuf, lin2t, eo, FF, DD);

  emit_out<<<SS, 256, 0, stream>>>(eo, mw, out);
}

// Round 8
// 337.442 us; speedup vs baseline: 2.6016x; 1.0093x over previous
//
#include <hip/hip_runtime.h>
#include <hip/hip_bf16.h>

// Problem constants (reference: B=32, S=2048, D=1024, F=512, E=8, GROUP=32 -> 1 group)
#define SS 2048
#define BB 32
#define DD 1024
#define FF 512
#define EE 8

typedef __attribute__((ext_vector_type(8))) short short8;
typedef __attribute__((ext_vector_type(8))) unsigned short ushort8v;
typedef __attribute__((ext_vector_type(4))) unsigned short ushort4v;
typedef __attribute__((ext_vector_type(4))) float f32x4;

__device__ inline unsigned short f2bf(float f) {
  union { float f; unsigned u; } v; v.f = f;
  return (unsigned short)((v.u + 0x7FFFu + ((v.u >> 16) & 1u)) >> 16);
}
__device__ inline float bf2f(unsigned short h) {
  union { unsigned u; float f; } v; v.u = ((unsigned)h) << 16;
  return v.f;
}

// ---------------- transpose + fp32->bf16 cast: in (E,K,N) f32 -> out (E,N,K) bf16
__global__ __launch_bounds__(256) void transpose_bf16(
    const float* __restrict__ in, unsigned short* __restrict__ out, int K, int N) {
  __shared__ float tile[32][33];
  int e = blockIdx.z;
  const float* inp = in + (size_t)e * K * N;
  unsigned short* outp = out + (size_t)e * K * N;
  int k0 = blockIdx.x * 32, n0 = blockIdx.y * 32;
  int tx = threadIdx.x;   // 0..31
  int ty = threadIdx.y;   // 0..7
#pragma unroll
  for (int i = 0; i < 4; i++) {
    int k = ty + i * 8;
    tile[k][tx] = inp[(size_t)(k0 + k) * N + n0 + tx];
  }
  __syncthreads();
#pragma unroll
  for (int i = 0; i < 4; i++) {
    int n = ty + i * 8;
    outp[(size_t)(n0 + n) * K + k0 + tx] = f2bf(tile[tx][n]);
  }
}

// ---------------- logits: lgT[s,k,e] = x_row[m=k*S+s] . ctrl[:,e]
__global__ __launch_bounds__(256) void logits_k(
    const float* __restrict__ x,      // (B,S,D) f32: row m = k*S + s
    const float* __restrict__ ctrl,   // (D,E) f32
    float* __restrict__ lgT) {        // (S,B,E) f32
  int t = threadIdx.x;
  __shared__ __align__(16) float cs[EE * DD];   // 32 KiB, [e][swz(d)]
  for (int i = t; i < DD * EE; i += 256) {
    int d = i >> 3, e = i & 7;
    cs[e * DD + (d ^ (((d >> 6) & 7) << 2))] = ctrl[i];
  }
  __syncthreads();

  int g = t >> 4, c = t & 15;
  int m0 = blockIdx.x * 64 + g * 4;
  const float* xr = x + (size_t)m0 * DD;
  float acc[4][8] = {};
#pragma unroll 4
  for (int i = 0; i < 16; i++) {
    int db = c * 4 + i * 64;
    float4 c4[8];
#pragma unroll
    for (int e = 0; e < 8; e++)
      c4[e] = *(const float4*)&cs[e * DD + i * 64 + ((c ^ (i & 7)) << 2)];
#pragma unroll
    for (int r = 0; r < 4; r++) {
      float4 xv = *(const float4*)&xr[(size_t)r * DD + db];
#pragma unroll
      for (int e = 0; e < 8; e++)
        acc[r][e] += xv.x * c4[e].x + xv.y * c4[e].y + xv.z * c4[e].z + xv.w * c4[e].w;
    }
  }
#pragma unroll
  for (int off = 1; off < 16; off <<= 1)
#pragma unroll
    for (int r = 0; r < 4; r++)
#pragma unroll
      for (int e = 0; e < 8; e++)
        acc[r][e] += __shfl_xor(acc[r][e], off, 64);
  if (c == 0) {
#pragma unroll
    for (int r = 0; r < 4; r++) {
      int m = m0 + r;
      int s = m & (SS - 1), k = m >> 11;
      float* p = &lgT[((size_t)s * BB + k) * EE];
      float4 lo = {acc[r][0], acc[r][1], acc[r][2], acc[r][3]};
      float4 hi = {acc[r][4], acc[r][5], acc[r][6], acc[r][7]};
      *(float4*)p = lo;
      *(float4*)(p + 4) = hi;
    }
  }
}

// ---------------- softmax over tokens k per (s,e); 8 s per block
__global__ __launch_bounds__(256) void softmax_k(
    const float* __restrict__ lgT,   // (S,B,E) f32
    float* __restrict__ mw) {        // (S,B,E) f32
  int t = threadIdx.x;
  int sl = t >> 5, k = t & 31;
  size_t s = (size_t)blockIdx.x * 8 + sl;
  const float* p = &lgT[(s * BB + k) * EE];
  float v[8];
  float4 lo = *(const float4*)p, hi = *(const float4*)(p + 4);
  v[0]=lo.x; v[1]=lo.y; v[2]=lo.z; v[3]=lo.w; v[4]=hi.x; v[5]=hi.y; v[6]=hi.z; v[7]=hi.w;
  float mx[8];
#pragma unroll
  for (int e = 0; e < 8; e++) mx[e] = v[e];
#pragma unroll
  for (int off = 1; off < 32; off <<= 1)
#pragma unroll
    for (int e = 0; e < 8; e++)
      mx[e] = fmaxf(mx[e], __shfl_xor(mx[e], off, 64));
  float pr[8], sm[8];
#pragma unroll
  for (int e = 0; e < 8; e++) { pr[e] = __expf(v[e] - mx[e]); sm[e] = pr[e]; }
#pragma unroll
  for (int off = 1; off < 32; off <<= 1)
#pragma unroll
    for (int e = 0; e < 8; e++)
      sm[e] += __shfl_xor(sm[e], off, 64);
  float4 o0 = {pr[0]/sm[0], pr[1]/sm[1], pr[2]/sm[2], pr[3]/sm[3]};
  float4 o1 = {pr[4]/sm[4], pr[5]/sm[5], pr[6]/sm[6], pr[7]/sm[7]};
  float* q = &mw[(s * BB + k) * EE];
  *(float4*)q = o0;
  *(float4*)(q + 4) = o1;
}

// ---------------- merge: merged[e,s,d] = sum_k mw[s,k,e] * x[k,s,d]   (E,S,D layout)
__global__ __launch_bounds__(256) void merge_v(
    const float* __restrict__ x,          // (B,S,D) f32
    const float* __restrict__ mw,         // (S,B,E) f32
    unsigned short* __restrict__ merged) {// (E,S,D) bf16
  int s = blockIdx.x;
  int t = threadIdx.x;
  __shared__ __align__(16) float wl[BB][EE];
  wl[t >> 3][t & 7] = mw[(size_t)s * BB * EE + t];
  __syncthreads();
  int d0 = t * 4;
  float a[8][4] = {};
#pragma unroll 4
  for (int k = 0; k < 32; k++) {
    float4 xv = *(const float4*)&x[((size_t)k * SS + s) * DD + d0];
    float4 wA = *(const float4*)&wl[k][0];
    float4 wB = *(const float4*)&wl[k][4];
    a[0][0] += wA.x * xv.x; a[0][1] += wA.x * xv.y; a[0][2] += wA.x * xv.z; a[0][3] += wA.x * xv.w;
    a[1][0] += wA.y * xv.x; a[1][1] += wA.y * xv.y; a[1][2] += wA.y * xv.z; a[1][3] += wA.y * xv.w;
    a[2][0] += wA.z * xv.x; a[2][1] += wA.z * xv.y; a[2][2] += wA.z * xv.z; a[2][3] += wA.z * xv.w;
    a[3][0] += wA.w * xv.x; a[3][1] += wA.w * xv.y; a[3][2] += wA.w * xv.z; a[3][3] += wA.w * xv.w;
    a[4][0] += wB.x * xv.x; a[4][1] += wB.x * xv.y; a[4][2] += wB.x * xv.z; a[4][3] += wB.x * xv.w;
    a[5][0] += wB.y * xv.x; a[5][1] += wB.y * xv.y; a[5][2] += wB.y * xv.z; a[5][3] += wB.y * xv.w;
    a[6][0] += wB.z * xv.x; a[6][1] += wB.z * xv.y; a[6][2] += wB.z * xv.z; a[6][3] += wB.z * xv.w;
    a[7][0] += wB.w * xv.x; a[7][1] += wB.w * xv.y; a[7][2] += wB.w * xv.z; a[7][3] += wB.w * xv.w;
  }
#pragma unroll
  for (int e = 0; e < 8; e++) {
    ushort4v pv;
    pv[0] = f2bf(a[e][0]); pv[1] = f2bf(a[e][1]);
    pv[2] = f2bf(a[e][2]); pv[3] = f2bf(a[e][3]);
    *(ushort4v*)&merged[((size_t)e * SS + s) * DD + d0] = pv;
  }
}

// ---------------- bf16 MFMA GEMM, double-buffered (T3-minimum 2-phase):
// raw barriers + counted vmcnt so next tile's global_load_lds stay in flight
// across the barrier (compiler's __syncthreads would force vmcnt(0) drain).
// A: (E, M=S, K) bf16 dense ; Bt: (E, N, K) bf16 ; C: (E, M, N) bf16 dense
// grid: (S/128, N/128, E), 256 threads = 4 waves (2x2), wave tile 64x64
template <int RELU>
__global__ __launch_bounds__(256) void gemm_bt(
    const unsigned short* __restrict__ A, const unsigned short* __restrict__ Bt,
    unsigned short* __restrict__ C, int K, int N) {
  int e = blockIdx.z;
  int m0 = blockIdx.x * 128;
  int n0 = blockIdx.y * 128;
  const unsigned short* Ae = A + (size_t)e * SS * K;
  const unsigned short* Be = Bt + (size_t)e * N * K;
  unsigned short* Ce = C + (size_t)e * SS * N;

  __shared__ __align__(16) unsigned short As[2][128 * 32];  // 2 x 8 KiB
  __shared__ __align__(16) unsigned short Bs[2][128 * 32];

  int t = threadIdx.x;
  int lane = t & 63, w = t >> 6;
  int wm = w >> 1, wn = w & 1;
  int lr = lane & 15;
  int kh = lane >> 4;
  int khs = kh ^ ((lr >> 1) & 3);

  // per-thread staging coordinates (2 chunks each for A and B)
  int c0 = t, c1 = t + 256;
  int r0 = c0 >> 2, r1 = c1 >> 2;
  int sg0 = (c0 & 3) ^ ((r0 >> 1) & 3);
  int sg1 = (c1 & 3) ^ ((r1 >> 1) & 3);

#define STAGE(buf, kt)                                                                        \
  do {                                                                                        \
    __builtin_amdgcn_global_load_lds(                                                         \
        (const __attribute__((address_space(1))) void*)(Ae + (size_t)(m0 + r0) * K + (kt) + sg0 * 8), \
        (__attribute__((address_space(3))) void*)(&As[buf][c0 * 8]), 16, 0, 0);               \
    __builtin_amdgcn_global_load_lds(                                                         \
        (const __attribute__((address_space(1))) void*)(Be + (size_t)(n0 + r0) * K + (kt) + sg0 * 8), \
        (__attribute__((address_space(3))) void*)(&Bs[buf][c0 * 8]), 16, 0, 0);               \
    __builtin_amdgcn_global_load_lds(                                                         \
        (const __attribute__((address_space(1))) void*)(Ae + (size_t)(m0 + r1) * K + (kt) + sg1 * 8), \
        (__attribute__((address_space(3))) void*)(&As[buf][c1 * 8]), 16, 0, 0);               \
    __builtin_amdgcn_global_load_lds(                                                         \
        (const __attribute__((address_space(1))) void*)(Be + (size_t)(n0 + r1) * K + (kt) + sg1 * 8), \
        (__attribute__((address_space(3))) void*)(&Bs[buf][c1 * 8]), 16, 0, 0);               \
  } while (0)

  f32x4 acc[4][4] = {};
  int nk = K / 32;

  STAGE(0, 0);  // prologue: 4 loads in flight

  for (int s = 0; s < nk; ++s) {
    int cur = s & 1;
    if (s + 1 < nk) {
      STAGE(cur ^ 1, (s + 1) * 32);              // issue next tile first (8 in flight)
      asm volatile("s_waitcnt vmcnt(4)" ::: "memory");  // oldest 4 (= cur tile) landed
    } else {
      asm volatile("s_waitcnt vmcnt(0)" ::: "memory");
    }
    __builtin_amdgcn_sched_barrier(0);
    __builtin_amdgcn_s_barrier();                // cur tile visible to all waves

    short8 af[4], bfr[4];
#pragma unroll
    for (int mi = 0; mi < 4; mi++)
      af[mi] = *(const short8*)&As[cur][(wm * 64 + mi * 16 + lr) * 32 + khs * 8];
#pragma unroll
    for (int ni = 0; ni < 4; ni++)
      bfr[ni] = *(const short8*)&Bs[cur][(wn * 64 + ni * 16 + lr) * 32 + khs * 8];
#pragma unroll
    for (int mi = 0; mi < 4; mi++)
#pragma unroll
      for (int ni = 0; ni < 4; ni++)
        acc[mi][ni] = __builtin_amdgcn_mfma_f32_16x16x32_bf16(af[mi], bfr[ni], acc[mi][ni], 0, 0, 0);

    // WAR fence: all waves done reading buf[cur] before next iter overwrites it.
    // NO vmcnt here — next tile's loads stay in flight across the barrier.
    asm volatile("s_waitcnt lgkmcnt(0)" ::: "memory");
    __builtin_amdgcn_sched_barrier(0);
    __builtin_amdgcn_s_barrier();
  }
#undef STAGE

  // epilogue: C/D layout col=lane&15, row=(lane>>4)*4+reg  [verified m89]
  int rb = (lane >> 4) * 4;
  int cb = lane & 15;
#pragma unroll
  for (int mi = 0; mi < 4; mi++)
#pragma unroll
    for (int ni = 0; ni < 4; ni++)
#pragma unroll
      for (int r = 0; r < 4; r++) {
        float v = acc[mi][ni][r];
        if (RELU) v = fmaxf(v, 0.f);
        int m = m0 + wm * 64 + mi * 16 + rb + r;
        int n = n0 + wn * 64 + ni * 16 + cb;
        Ce[(size_t)m * N + n] = f2bf(v);
      }
}

// ---------------- emit: out[b,s,d] = sum_e mw[s,b,e] * eo[e,s,d]
__global__ __launch_bounds__(256) void emit_out(
    const unsigned short* __restrict__ eo,  // (E,S,D) bf16
    const float* __restrict__ mw,           // (S,B,E) f32
    float* __restrict__ out) {              // (B,S,D) f32
  int s = blockIdx.x;
  int t = threadIdx.x;
  __shared__ float wsm[BB][EE];
  wsm[t >> 3][t & 7] = mw[(size_t)s * BB * EE + t];
  __syncthreads();
  int d0 = t * 4;
  float ev[EE][4];
#pragma unroll
  for (int e2 = 0; e2 < 8; e2++) {
    ushort4v v = *(const ushort4v*)&eo[((size_t)e2 * SS + s) * DD + d0];
    ev[e2][0] = bf2f(v[0]); ev[e2][1] = bf2f(v[1]);
    ev[e2][2] = bf2f(v[2]); ev[e2][3] = bf2f(v[3]);
  }
  for (int b = 0; b < BB; b++) {
    float o0 = 0.f, o1 = 0.f, o2 = 0.f, o3 = 0.f;
#pragma unroll
    for (int e2 = 0; e2 < 8; e2++) {
      float we = wsm[b][e2];
      o0 += we * ev[e2][0]; o1 += we * ev[e2][1];
      o2 += we * ev[e2][2]; o3 += we * ev[e2][3];
    }
    float4 ov = {o0, o1, o2, o3};
    *(float4*)&out[((size_t)b * SS + s) * DD + d0] = ov;
  }
}

extern "C" void kernel_launch(void* const* d_in, const int* in_sizes, int n_in,
                              void* d_out, int out_size, void* d_ws, size_t ws_size,
                              hipStream_t stream) {
  const float* x = (const float*)d_in[0];        // (32, 2048, 1024)
  const float* lin1 = (const float*)d_in[1];     // (8, 1024, 512)
  const float* lin2 = (const float*)d_in[2];     // (8, 512, 1024)
  const float* ctrl = (const float*)d_in[3];     // (1024, 8)
  float* out = (float*)d_out;

  char* ws = (char*)d_ws;
  size_t off = 0;
  unsigned short* lin1t = (unsigned short*)(ws + off); off += (size_t)EE * DD * FF * 2;  // 8 MiB
  unsigned short* lin2t = (unsigned short*)(ws + off); off += (size_t)EE * FF * DD * 2;  // 8 MiB
  unsigned short* merged = (unsigned short*)(ws + off); off += (size_t)SS * EE * DD * 2; // 32 MiB (E,S,D)
  unsigned short* hbuf = (unsigned short*)(ws + off); off += (size_t)SS * EE * FF * 2;   // 16 MiB (E,S,F)
  unsigned short* eo = (unsigned short*)(ws + off); off += (size_t)SS * EE * DD * 2;     // 32 MiB (E,S,D)
  float* mw = (float*)(ws + off); off += (size_t)SS * BB * EE * 4;                       // 2 MiB
  float* lgT = (float*)(ws + off); off += (size_t)SS * BB * EE * 4;                      // 2 MiB

  dim3 tb(32, 8);
  transpose_bf16<<<dim3(DD / 32, FF / 32, EE), tb, 0, stream>>>(lin1, lin1t, DD, FF);
  transpose_bf16<<<dim3(FF / 32, DD / 32, EE), tb, 0, stream>>>(lin2, lin2t, FF, DD);

  logits_k<<<(SS * BB) / 64, 256, 0, stream>>>(x, ctrl, lgT);
  softmax_k<<<SS / 8, 256, 0, stream>>>(lgT, mw);
  merge_v<<<SS, 256, 0, stream>>>(x, mw, merged);

  // h = relu(merged @ lin1): per-expert dense M=S, K=D, N=F
  gemm_bt<1><<<dim3(SS / 128, FF / 128, EE), 256, 0, stream>>>(merged, lin1t, hbuf, DD, FF);
  // eo = h @ lin2: K=F, N=D
  gemm_bt<0><<<dim3(SS / 128, DD / 128, EE), 256, 0, stream>>>(hbuf, lin2t, eo, FF, DD);

  emit_out<<<SS, 256, 0, stream>>>(eo, mw, out);
}